// Round 1
// baseline (587.344 us; speedup 1.0000x reference)
//
#include <hip/hip_runtime.h>
#include <hip/hip_bf16.h>

// SocialGNN: 2-layer GCN, N=100000 nodes, E=1600000 edges (+ self loops),
// feat 256 -> 128 (relu) -> 16, fp32 throughout.
//
// Strategy:
//   norm_ij = dinv[src]*dinv[dst]  =>  out_i = dinv_i * sum_{j in N(i)} (h_j * dinv_j)
//   so: pre-scale rows by dinv in the GEMM epilogue, post-scale after aggregation.
//   Aggregation uses a device-built CSR (by dst) shared by both layers:
//   histogram -> 2-level scan -> scatter. Per-node register accumulation,
//   no fp32 atomics in the hot path.

#define N_FEAT_IN 256
#define N_FEAT_MID 128
#define N_FEAT_OUT 16

// ---------------- degree histogram ----------------
__global__ void k_hist(const int* __restrict__ dst, int* __restrict__ cnt, int E) {
    int e = blockIdx.x * 256 + threadIdx.x;
    if (e < E) atomicAdd(&cnt[dst[e]], 1);
}

__global__ void k_dinv(const int* __restrict__ cnt, float* __restrict__ dinv, int n) {
    int i = blockIdx.x * 256 + threadIdx.x;
    if (i < n) dinv[i] = 1.0f / sqrtf((float)cnt[i] + 1.0f);  // +1 self-loop
}

// ---------------- 2-level exclusive scan (chunk = 1024) ----------------
__global__ void k_scan_s1(const int* __restrict__ cnt, int* __restrict__ bsum, int n) {
    __shared__ int ts[256];
    int t = threadIdx.x;
    int base = blockIdx.x * 1024 + t * 4;
    int s = 0;
#pragma unroll
    for (int j = 0; j < 4; ++j) { int i = base + j; if (i < n) s += cnt[i]; }
    ts[t] = s; __syncthreads();
    for (int off = 128; off > 0; off >>= 1) {
        if (t < off) ts[t] += ts[t + off];
        __syncthreads();
    }
    if (t == 0) bsum[blockIdx.x] = ts[0];
}

__global__ void k_scan_s2(const int* __restrict__ bsum, int* __restrict__ boff,
                          int nb, int* __restrict__ row_ptr, int n) {
    __shared__ int ts[128];
    int t = threadIdx.x;
    int v = (t < nb) ? bsum[t] : 0;
    ts[t] = v; __syncthreads();
    for (int off = 1; off < 128; off <<= 1) {
        int x = (t >= off) ? ts[t - off] : 0;
        __syncthreads();
        ts[t] += x;
        __syncthreads();
    }
    if (t < nb) boff[t] = ts[t] - v;       // exclusive
    if (t == 127) row_ptr[n] = ts[127];    // total edge count
}

__global__ void k_scan_s3(const int* __restrict__ cnt, const int* __restrict__ boff,
                          int* __restrict__ row_ptr, int* __restrict__ cursor, int n) {
    __shared__ int ts[256];
    int t = threadIdx.x;
    int base = blockIdx.x * 1024 + t * 4;
    int v[4];
#pragma unroll
    for (int j = 0; j < 4; ++j) { int i = base + j; v[j] = (i < n) ? cnt[i] : 0; }
    int tsum = v[0] + v[1] + v[2] + v[3];
    ts[t] = tsum; __syncthreads();
    for (int off = 1; off < 256; off <<= 1) {
        int x = (t >= off) ? ts[t - off] : 0;
        __syncthreads();
        ts[t] += x;
        __syncthreads();
    }
    int excl = ts[t] - tsum + boff[blockIdx.x];
#pragma unroll
    for (int j = 0; j < 4; ++j) {
        int i = base + j;
        if (i < n) { row_ptr[i] = excl; cursor[i] = excl; }
        excl += v[j];
    }
}

__global__ void k_scatter(const int* __restrict__ src, const int* __restrict__ dst,
                          int* __restrict__ cursor, int* __restrict__ csr, int E) {
    int e = blockIdx.x * 256 + threadIdx.x;
    if (e < E) {
        int pos = atomicAdd(&cursor[dst[e]], 1);
        csr[pos] = src[e];
    }
}

// ---------------- GEMM1: X[M,256] @ W1[256,128], epilogue *dinv[row] ----------------
// BM=64 BN=128 BK=32, 256 threads, thread tile 4x8.
__global__ __launch_bounds__(256) void k_gemm1(const float* __restrict__ X,
                                               const float* __restrict__ W1,
                                               const float* __restrict__ dinv,
                                               float* __restrict__ h1s, int M) {
    __shared__ float As[32][68];   // [k][m], pad 68 (16B aligned rows, conflict-light)
    __shared__ float Bs[32][128];  // [k][n]
    const int tid = threadIdx.x;
    const int block_row = blockIdx.x * 64;
    const int tr = (tid >> 4) * 4;   // 0..60
    const int tc = (tid & 15) * 8;   // 0..120
    float acc[4][8];
#pragma unroll
    for (int r = 0; r < 4; ++r)
#pragma unroll
        for (int c = 0; c < 8; ++c) acc[r][c] = 0.0f;

    for (int k0 = 0; k0 < 256; k0 += 32) {
        // A tile: 64x32 floats = 512 float4, 2 per thread
#pragma unroll
        for (int i = 0; i < 2; ++i) {
            int fa = tid + i * 256;
            int m = fa >> 3;
            int kq = fa & 7;
            int row = block_row + m;
            if (row >= M) row = M - 1;  // clamp; masked at store
            float4 v = *(const float4*)(X + (size_t)row * 256 + k0 + kq * 4);
            As[kq * 4 + 0][m] = v.x;
            As[kq * 4 + 1][m] = v.y;
            As[kq * 4 + 2][m] = v.z;
            As[kq * 4 + 3][m] = v.w;
        }
        // B tile: 32x128 floats = 1024 float4, 4 per thread
#pragma unroll
        for (int i = 0; i < 4; ++i) {
            int fb = tid + i * 256;
            int kr = fb >> 5;
            int nc = (fb & 31) * 4;
            *(float4*)(&Bs[kr][nc]) = *(const float4*)(W1 + (size_t)(k0 + kr) * 128 + nc);
        }
        __syncthreads();
#pragma unroll
        for (int kk = 0; kk < 32; ++kk) {
            float a[4], b[8];
            *(float4*)a = *(const float4*)(&As[kk][tr]);
            *(float4*)(b + 0) = *(const float4*)(&Bs[kk][tc]);
            *(float4*)(b + 4) = *(const float4*)(&Bs[kk][tc + 4]);
#pragma unroll
            for (int r = 0; r < 4; ++r)
#pragma unroll
                for (int c = 0; c < 8; ++c) acc[r][c] += a[r] * b[c];
        }
        __syncthreads();
    }
#pragma unroll
    for (int r = 0; r < 4; ++r) {
        int row = block_row + tr + r;
        if (row < M) {
            float dv = dinv[row];
            float4 o0 = make_float4(acc[r][0] * dv, acc[r][1] * dv, acc[r][2] * dv, acc[r][3] * dv);
            float4 o1 = make_float4(acc[r][4] * dv, acc[r][5] * dv, acc[r][6] * dv, acc[r][7] * dv);
            *(float4*)(h1s + (size_t)row * 128 + tc) = o0;
            *(float4*)(h1s + (size_t)row * 128 + tc + 4) = o1;
        }
    }
}

// ---------------- agg1: one wave per node, 128 feats as float2/lane ----------------
__global__ __launch_bounds__(256) void k_agg1(const float* __restrict__ h1s,
                                              const int* __restrict__ rp,
                                              const int* __restrict__ csr,
                                              const float* __restrict__ dinv,
                                              const float* __restrict__ b1,
                                              float* __restrict__ tbuf, int n) {
    int w = (blockIdx.x * 256 + threadIdx.x) >> 6;  // global wave = node
    int lane = threadIdx.x & 63;
    if (w >= n) return;
    const float2* hv = (const float2*)h1s;
    float2 acc = hv[(size_t)w * 64 + lane];  // self-loop contribution (h already *dinv)
    int start = rp[w], end = rp[w + 1];
    int e = start;
    for (; e + 4 <= end; e += 4) {
        int s0 = csr[e], s1 = csr[e + 1], s2 = csr[e + 2], s3 = csr[e + 3];
        float2 v0 = hv[(size_t)s0 * 64 + lane];
        float2 v1 = hv[(size_t)s1 * 64 + lane];
        float2 v2 = hv[(size_t)s2 * 64 + lane];
        float2 v3 = hv[(size_t)s3 * 64 + lane];
        acc.x += (v0.x + v1.x) + (v2.x + v3.x);
        acc.y += (v0.y + v1.y) + (v2.y + v3.y);
    }
    for (; e < end; ++e) {
        float2 v = hv[(size_t)csr[e] * 64 + lane];
        acc.x += v.x; acc.y += v.y;
    }
    float dv = dinv[w];
    float2 bb = ((const float2*)b1)[lane];
    float tx = fmaxf(dv * acc.x + bb.x, 0.0f);
    float ty = fmaxf(dv * acc.y + bb.y, 0.0f);
    ((float2*)tbuf)[(size_t)w * 64 + lane] = make_float2(tx, ty);
}

// ---------------- GEMM2: t[n,128] @ W2[128,16], *dinv[row] ----------------
__global__ __launch_bounds__(256) void k_gemm2(const float* __restrict__ tbuf,
                                               const float* __restrict__ W2,
                                               const float* __restrict__ dinv,
                                               float* __restrict__ h2s, int n) {
    __shared__ float w2s[128 * 16];
    for (int i = threadIdx.x; i < 2048; i += 256) w2s[i] = W2[i];
    __syncthreads();
    int gid = blockIdx.x * 256 + threadIdx.x;
    int node = gid >> 4;
    int o = gid & 15;
    if (node >= n) return;
    const float4* tv = (const float4*)(tbuf + (size_t)node * 128);
    float acc = 0.0f;
#pragma unroll
    for (int k4 = 0; k4 < 32; ++k4) {
        float4 v = tv[k4];
        acc += v.x * w2s[(k4 * 4 + 0) * 16 + o];
        acc += v.y * w2s[(k4 * 4 + 1) * 16 + o];
        acc += v.z * w2s[(k4 * 4 + 2) * 16 + o];
        acc += v.w * w2s[(k4 * 4 + 3) * 16 + o];
    }
    h2s[(size_t)node * 16 + o] = acc * dinv[node];
}

// ---------------- agg2: 16 lanes per node ----------------
__global__ __launch_bounds__(256) void k_agg2(const float* __restrict__ h2s,
                                              const int* __restrict__ rp,
                                              const int* __restrict__ csr,
                                              const float* __restrict__ dinv,
                                              const float* __restrict__ b2,
                                              float* __restrict__ out, int n) {
    int gid = blockIdx.x * 256 + threadIdx.x;
    int node = gid >> 4;
    int o = gid & 15;
    if (node >= n) return;
    float acc = h2s[(size_t)node * 16 + o];  // self loop
    int start = rp[node], end = rp[node + 1];
    int e = start;
    for (; e + 4 <= end; e += 4) {
        int s0 = csr[e], s1 = csr[e + 1], s2 = csr[e + 2], s3 = csr[e + 3];
        float v0 = h2s[(size_t)s0 * 16 + o];
        float v1 = h2s[(size_t)s1 * 16 + o];
        float v2 = h2s[(size_t)s2 * 16 + o];
        float v3 = h2s[(size_t)s3 * 16 + o];
        acc += (v0 + v1) + (v2 + v3);
    }
    for (; e < end; ++e) acc += h2s[(size_t)csr[e] * 16 + o];
    out[(size_t)node * 16 + o] = dinv[node] * acc + b2[o];
}

extern "C" void kernel_launch(void* const* d_in, const int* in_sizes, int n_in,
                              void* d_out, int out_size, void* d_ws, size_t ws_size,
                              hipStream_t stream) {
    const float* X  = (const float*)d_in[0];
    const int*   ei = (const int*)d_in[1];   // harness delivers integer inputs as int32
    const float* W1 = (const float*)d_in[2];
    const float* b1 = (const float*)d_in[3];
    const float* W2 = (const float*)d_in[4];
    const float* b2 = (const float*)d_in[5];
    float* out = (float*)d_out;

    const int n = in_sizes[0] / N_FEAT_IN;   // 100000
    const int E = in_sizes[1] / 2;           // 1600000
    const int* src = ei;
    const int* dst = ei + E;

    char* ws = (char*)d_ws;
    size_t off = 0;
    auto alloc = [&](size_t bytes) -> char* {
        char* p = ws + off;
        off = (off + bytes + 255) & ~(size_t)255;
        return p;
    };
    int*   cnt     = (int*)alloc((size_t)n * 4);
    float* dinv    = (float*)alloc((size_t)n * 4);
    int*   row_ptr = (int*)alloc((size_t)(n + 1) * 4);
    int*   cursor  = (int*)alloc((size_t)(n + 1) * 4);
    int*   bsum    = (int*)alloc(128 * 4);
    int*   boff    = (int*)alloc(128 * 4);
    int*   csr     = (int*)alloc((size_t)E * 4);
    float* h1s     = (float*)alloc((size_t)n * 128 * 4);
    float* tbuf    = (float*)alloc((size_t)n * 128 * 4);
    float* h2s     = (float*)alloc((size_t)n * 16 * 4);
    (void)ws_size;

    const int NB = (n + 1023) / 1024;  // 98 <= 128

    hipMemsetAsync(cnt, 0, (size_t)n * 4, stream);

    int eb = (E + 255) / 256;
    k_hist<<<eb, 256, 0, stream>>>(dst, cnt, E);
    k_dinv<<<(n + 255) / 256, 256, 0, stream>>>(cnt, dinv, n);
    k_scan_s1<<<NB, 256, 0, stream>>>(cnt, bsum, n);
    k_scan_s2<<<1, 128, 0, stream>>>(bsum, boff, NB, row_ptr, n);
    k_scan_s3<<<NB, 256, 0, stream>>>(cnt, boff, row_ptr, cursor, n);
    k_scatter<<<eb, 256, 0, stream>>>(src, dst, cursor, csr, E);

    k_gemm1<<<(n + 63) / 64, 256, 0, stream>>>(X, W1, dinv, h1s, n);
    k_agg1<<<(n + 3) / 4, 256, 0, stream>>>(h1s, row_ptr, csr, dinv, b1, tbuf, n);
    k_gemm2<<<((size_t)n * 16 + 255) / 256, 256, 0, stream>>>(tbuf, W2, dinv, h2s, n);
    k_agg2<<<((size_t)n * 16 + 255) / 256, 256, 0, stream>>>(h2s, row_ptr, csr, dinv, b2, out, n);
}